// Round 9
// baseline (218.140 us; speedup 1.0000x reference)
//
#include <hip/hip_runtime.h>
#include <stdint.h>

typedef __attribute__((ext_vector_type(4)))  int   intx4;
typedef __attribute__((ext_vector_type(8)))  int   intx8;
typedef __attribute__((ext_vector_type(16))) float floatx16;

#define GLL16(gp, lp)                                                               \
    __builtin_amdgcn_global_load_lds((const __attribute__((address_space(1))) unsigned int*)(gp), \
                                     (__attribute__((address_space(3))) unsigned int*)(lp), 16, 0, 0)
#define GLL4(gp, lp)                                                                \
    __builtin_amdgcn_global_load_lds((const __attribute__((address_space(1))) unsigned int*)(gp), \
                                     (__attribute__((address_space(3))) unsigned int*)(lp), 4, 0, 0)

// ---------------------------------------------------------------------------
// RTE onto the e2m1 grid {0,.5,1,1.5,2,3,4,6} -> code 0..7 (ties-to-even,
// matches ref searchsorted+tie-fix). Sign -> bit 3. (proven)
// ---------------------------------------------------------------------------
__device__ __forceinline__ uint32_t enc1(float xv, float inv) {
    float a = fminf(fabsf(xv) * inv, 6.0f);
    int e;
    if (a < 2.0f)      e = (int)rintf(a + a);          // 0,.5,1,1.5,2 -> 0..4
    else if (a < 4.0f) e = (int)rintf(a) + 2;          // 2,3,4        -> 4..6
    else               e = (int)rintf(a * 0.5f) + 4;   // 4,6          -> 6,7
    return (uint32_t)e | ((__float_as_uint(xv) >> 28) & 8u);
}

// ---------------------------------------------------------------------------
// Kernel 1: quantize x (proven rounds 1-8). All accesses coalesced; scales
// to NATURAL layout xs[m*kbpr+kb].
// ---------------------------------------------------------------------------
__global__ __launch_bounds__(256) void quant_x_kernel(const float* __restrict__ x,
                                                      uint32_t* __restrict__ xq,
                                                      uint8_t* __restrict__ xs) {
    const int gl = blockIdx.x * 256 + threadIdx.x;          // lane over M*K/4
    const float4 v = ((const float4*)x)[gl];
    float m = fmaxf(fmaxf(fabsf(v.x), fabsf(v.y)), fmaxf(fabsf(v.z), fabsf(v.w)));
    m = fmaxf(m, __shfl_xor(m, 1));
    m = fmaxf(m, __shfl_xor(m, 2));
    m = fmaxf(m, __shfl_xor(m, 4));                         // 8-lane group = 1 MX block
    const unsigned ef = __float_as_uint(m) >> 23;
    const unsigned code = (ef < 3u) ? 1u : (ef - 2u);       // FLOOR scale, clamped
    const float inv = __uint_as_float((254u - code) << 23); // exact 2^(127-code)
    const uint32_t p = enc1(v.x, inv)        | (enc1(v.y, inv) << 4)
                     | (enc1(v.z, inv) << 8) | (enc1(v.w, inv) << 12);
    ((uint16_t*)xq)[gl] = (uint16_t)p;                      // coalesced 2 B/lane
    if ((gl & 7) == 0) xs[gl >> 3] = (uint8_t)code;         // coalesced byte/8 lanes
}

// ---------------------------------------------------------------------------
// Kernel 2 (merged, proven round 8): wrep densify + scale transposes.
// ---------------------------------------------------------------------------
__global__ __launch_bounds__(256) void repack_kernel(const int* __restrict__ wp,
                                                     uint32_t* __restrict__ wrep,
                                                     int nwb,
                                                     const uint8_t* __restrict__ xs,
                                                     const int* __restrict__ wsc,
                                                     uint8_t* __restrict__ xs_t,
                                                     uint8_t* __restrict__ ws_t,
                                                     int R, int Ck) {
    const int bid = blockIdx.x;
    const int t = threadIdx.x;
    if (bid < nwb) {                              // ---- wrep densify ----
        const int i = bid * 256 + t;
        const int4 p = ((const int4*)wp)[i];
        wrep[i] = (uint32_t)(p.x & 0xFF) | ((uint32_t)(p.y & 0xFF) << 8)
                | ((uint32_t)(p.z & 0xFF) << 16) | ((uint32_t)(p.w & 0xFF) << 24);
        return;
    }
    // ---- scale transpose: tile 128 rows x 32 kb ----
    __shared__ uint8_t raw[128 * 32];
    const int tidx = bid - nwb;                   // 0..255
    const int r0 = (tidx & 63) * 128;             // combined row base (0..8191)
    const int c0 = (tidx >> 6) * 32;              // kb base (0..96)
    const int r = t >> 1, hf = t & 1;
    if (r0 < R) {                                 // source: xs (uint8)
        const uint4 v = *(const uint4*)(xs + (size_t)(r0 + r) * Ck + c0 + hf * 16);
        *(uint4*)(raw + r * 32 + hf * 16) = v;
    } else {                                      // source: wsc (int32 input)
        const size_t base = (size_t)(r0 - R + r) * Ck + c0 + hf * 16;
        uint32_t b[4];
#pragma unroll
        for (int j = 0; j < 4; ++j) {
            const int4 p = *(const int4*)(wsc + base + 4 * j);
            b[j] = (uint32_t)(p.x & 0xFF) | ((uint32_t)(p.y & 0xFF) << 8)
                 | ((uint32_t)(p.z & 0xFF) << 16) | ((uint32_t)(p.w & 0xFF) << 24);
        }
        *(uint4*)(raw + r * 32 + hf * 16) = make_uint4(b[0], b[1], b[2], b[3]);
    }
    __syncthreads();
    const int c = t >> 3, q = t & 7;
    uint32_t d[4];
#pragma unroll
    for (int j = 0; j < 4; ++j) {
        const int mb = q * 16 + j * 4;
        d[j] = (uint32_t)raw[(mb + 0) * 32 + c]
             | ((uint32_t)raw[(mb + 1) * 32 + c] << 8)
             | ((uint32_t)raw[(mb + 2) * 32 + c] << 16)
             | ((uint32_t)raw[(mb + 3) * 32 + c] << 24);
    }
    uint8_t* outp = (r0 < R) ? (xs_t + (size_t)(c0 + c) * R + r0)
                             : (ws_t + (size_t)(c0 + c) * R + (r0 - R));
    *(uint4*)(outp + q * 16) = make_uint4(d[0], d[1], d[2], d[3]);
}

// ---------------------------------------------------------------------------
// Kernel 3: MXFP4 GEMM, 128x128 tile, BK=256, 4 waves x (2x2)
// v_mfma_scale_f32_32x32x64_f8f6f4 (fmt 4 = fp4 e2m1).
//
// Round-9 changes vs round-6 (best, 55.7 us):
//  1. XCD swizzle REVERTED (round 8: +32 MB fetch, -12% — default co-resident
//     dispatch already gives each XCD a 1 MB B working set).
//  2. B operand DIRECT-TO-REGISTER (flatmm-style): each lane's B fragment is
//     an aligned dwordx4 at Bpk[br*Kb + (8c+kp)*16] — no sB staging, no sB
//     reads. LDS traffic per CU per chunk drops ~2.2x (the dominant pipe);
//     B re-reads (2 waves/row) hit L1/L2 (16 KB chunk slice, L2-hot).
//     LDS 34.8 -> 18.4 KB; occupancy stays 4 blocks/CU.
//
// Proven kept: single buffer + 2x __syncthreads, A piece-swizzle p=w^(r&7),
// coalesced transposed-scale GLL4 staging (A+B scales in sS).
// ---------------------------------------------------------------------------
__global__ __launch_bounds__(256) void gemm_mx_kernel(const uint8_t* __restrict__ Apk,
                                                      const uint8_t* __restrict__ Bpk,
                                                      const uint8_t* __restrict__ AsT,
                                                      const uint8_t* __restrict__ BsT,
                                                      float* __restrict__ C,
                                                      int M, int N, int K) {
    __shared__ __align__(16) uint8_t sA[16384];   // 128 rows x 128 B
    __shared__ __align__(16) uint8_t sS[2048];    // [A kb0..7][row] | [B kb0..7][row]

    const int tid = threadIdx.x;
    const int bm0 = blockIdx.y << 7;
    const int bn0 = blockIdx.x << 7;
    const int wave = tid >> 6;
    const int lane = tid & 63;
    const int wm = (wave >> 1) << 6;
    const int wn = (wave & 1) << 6;
    const int row = lane & 31;
    const int h = lane >> 5;
    const int Kb = K >> 1;                        // packed bytes per row (2048)

    // A staging: 1024 slots (128 rows x 8 pieces), 4 slots/thread.
    // slot s: row r = s>>3, within-row slot w = s&7, piece p = w ^ (r&7)
    const uint8_t* Ag[4];
#pragma unroll
    for (int i = 0; i < 4; ++i) {
        const int s = tid + 256 * i;
        const int r = s >> 3;
        const int p = (s & 7) ^ (r & 7);
        Ag[i] = Apk + (size_t)(bm0 + r) * Kb + p * 16;
    }

    // scale staging (coalesced, transposed arrays): waves 0-1 -> A, 2-3 -> B.
    const int st = tid & 127;
    const int sj = st >> 5, si = st & 31;
    const size_t sR = (size_t)((tid < 128) ? M : N);
    const uint8_t* Sg1 = ((tid < 128) ? (AsT + (size_t)sj * M + bm0)
                                      : (BsT + (size_t)sj * N + bn0)) + si * 4;
    const uint8_t* Sg2 = Sg1 + 4 * sR;
    const size_t sAdv = 8 * sR;
    const int soff = ((tid < 128) ? 0 : 1024) + st * 4;

    // B direct-to-register bases: lane (col br, k-half h)
    const int br0 = wn + row, br1 = wn + 32 + row;
    const uint8_t* Bg0 = Bpk + (size_t)(bn0 + br0) * Kb + h * 16;
    const uint8_t* Bg1 = Bpk + (size_t)(bn0 + br1) * Kb + h * 16;

    floatx16 acc[2][2];
#pragma unroll
    for (int a = 0; a < 2; ++a)
#pragma unroll
        for (int b = 0; b < 2; ++b)
#pragma unroll
            for (int r = 0; r < 16; ++r) acc[a][b][r] = 0.f;

    const int nchunk = K >> 8;                    // 16
    const int ar0 = wm + row, ar1 = wm + 32 + row;

    for (int c = 0; c < nchunk; ++c) {
        __syncthreads();
        const size_t koff = (size_t)c << 7;       // 128 B per chunk
#pragma unroll
        for (int i = 0; i < 4; ++i) GLL16(Ag[i] + koff, sA + (tid + 256 * i) * 16);
        GLL4(Sg1 + (size_t)c * sAdv, sS + soff);
        GLL4(Sg2 + (size_t)c * sAdv, sS + soff + 512);
        // B fragments for this chunk -> registers (independent of LDS; the
        // implicit vmcnt(0) at the barrier below also covers them)
        intx4 b4[4][2];
#pragma unroll
        for (int s = 0; s < 4; ++s) {
            b4[s][0] = *(const intx4*)(Bg0 + koff + s * 32);
            b4[s][1] = *(const intx4*)(Bg1 + koff + s * 32);
        }
        __syncthreads();

#pragma unroll
        for (int s = 0; s < 4; ++s) {
            const int kp = 2 * s + h;             // 16B piece / MX-block index 0..7
            intx4 a4[2];
            int sa[2], sb[2];
            a4[0] = *(const intx4*)(sA + ar0 * 128 + ((kp ^ (ar0 & 7)) << 4));
            a4[1] = *(const intx4*)(sA + ar1 * 128 + ((kp ^ (ar1 & 7)) << 4));
            sa[0] = sS[kp * 128 + ar0];
            sa[1] = sS[kp * 128 + ar1];
            sb[0] = sS[1024 + kp * 128 + br0];
            sb[1] = sS[1024 + kp * 128 + br1];
#pragma unroll
            for (int mt = 0; mt < 2; ++mt)
#pragma unroll
                for (int nt = 0; nt < 2; ++nt) {
                    intx8 a8 = {a4[mt][0], a4[mt][1], a4[mt][2], a4[mt][3], 0, 0, 0, 0};
                    intx8 b8 = {b4[s][nt][0], b4[s][nt][1], b4[s][nt][2], b4[s][nt][3], 0, 0, 0, 0};
                    acc[mt][nt] = __builtin_amdgcn_mfma_scale_f32_32x32x64_f8f6f4(
                        a8, b8, acc[mt][nt], 4, 4, 0, sa[mt], 0, sb[nt]);
                }
        }
    }

    // C/D layout (32x32): col = lane&31, row = (reg&3) + 8*(reg>>2) + 4*(lane>>5)
#pragma unroll
    for (int mt = 0; mt < 2; ++mt)
#pragma unroll
        for (int nt = 0; nt < 2; ++nt) {
            const int col = bn0 + wn + nt * 32 + row;
#pragma unroll
            for (int g = 0; g < 4; ++g) {
                const int rw = bm0 + wm + mt * 32 + 8 * g + 4 * h;
#pragma unroll
                for (int q = 0; q < 4; ++q)
                    C[(size_t)(rw + q) * N + col] = acc[mt][nt][4 * g + q];
            }
        }
}

// ---------------------------------------------------------------------------
extern "C" void kernel_launch(void* const* d_in, const int* in_sizes, int n_in,
                              void* d_out, int out_size, void* d_ws, size_t ws_size,
                              hipStream_t stream) {
    const float* x = (const float*)d_in[0];
    const int* wp = (const int*)d_in[1];
    const int* wsc = (const int*)d_in[2];
    float* out = (float*)d_out;

    const int K = 4096;
    const int M = in_sizes[0] / K;            // 4096
    const int N = (in_sizes[1] * 2) / K;      // 4096
    const int kbpr = K / 32;                  // 128
    const int npack = N * K / 2;              // weight packed bytes

    uint32_t* xq   = (uint32_t*)d_ws;                                  // 8 MiB
    uint8_t*  xs   = (uint8_t*)d_ws + (size_t)M * K / 2;               // 512 KiB [m][kb]
    uint32_t* wrep = (uint32_t*)(xs + (size_t)M * kbpr);               // 8 MiB
    uint8_t*  xs_t = (uint8_t*)(wrep + (size_t)npack / 4);             // 512 KiB [kb][m]
    uint8_t*  ws_t = xs_t + (size_t)M * kbpr;                          // 512 KiB [kb][n]

    const int nwb = npack / 4 / 256;          // wrep blocks (8192)
    const int ntb = (2 * M / 128) * (kbpr / 32);  // transpose tiles (256)

    quant_x_kernel<<<(M * K / 4) / 256, 256, 0, stream>>>(x, xq, xs);
    repack_kernel<<<nwb + ntb, 256, 0, stream>>>(wp, wrep, nwb,
                                                 xs, wsc, xs_t, ws_t, M, kbpr);

    dim3 grid(N / 128, M / 128);
    gemm_mx_kernel<<<grid, 256, 0, stream>>>((const uint8_t*)xq, (const uint8_t*)wrep,
                                             xs_t, ws_t, out, M, N, K);
}

// Round 10
// 191.428 us; speedup vs baseline: 1.1395x; 1.1395x over previous
//
#include <hip/hip_runtime.h>
#include <stdint.h>

typedef __attribute__((ext_vector_type(4)))  int   intx4;
typedef __attribute__((ext_vector_type(8)))  int   intx8;
typedef __attribute__((ext_vector_type(16))) float floatx16;

#define GLL16(gp, lp)                                                               \
    __builtin_amdgcn_global_load_lds((const __attribute__((address_space(1))) unsigned int*)(gp), \
                                     (__attribute__((address_space(3))) unsigned int*)(lp), 16, 0, 0)

// ---------------------------------------------------------------------------
// RTE onto the e2m1 grid {0,.5,1,1.5,2,3,4,6} -> code 0..7 (ties-to-even,
// matches ref searchsorted+tie-fix). Sign -> bit 3. (proven)
// ---------------------------------------------------------------------------
__device__ __forceinline__ uint32_t enc1(float xv, float inv) {
    float a = fminf(fabsf(xv) * inv, 6.0f);
    int e;
    if (a < 2.0f)      e = (int)rintf(a + a);          // 0,.5,1,1.5,2 -> 0..4
    else if (a < 4.0f) e = (int)rintf(a) + 2;          // 2,3,4        -> 4..6
    else               e = (int)rintf(a * 0.5f) + 4;   // 4,6          -> 6,7
    return (uint32_t)e | ((__float_as_uint(xv) >> 28) & 8u);
}

// ---------------------------------------------------------------------------
// Kernel 1: quantize x (proven core). NEW: scale bytes go directly to the
// packed-interleaved layout xsi[chunk][m][h][j], where byte h*4+j holds the
// scale of kb = 8*chunk + 2*j + h. (32 scattered byte-stores per block in
// 4 8-byte clusters — negligible vs the 8 KB xq write.)
// ---------------------------------------------------------------------------
__global__ __launch_bounds__(256) void quant_x_kernel(const float* __restrict__ x,
                                                      uint32_t* __restrict__ xq,
                                                      uint8_t* __restrict__ xsi,
                                                      int M) {
    const int gl = blockIdx.x * 256 + threadIdx.x;          // lane over M*K/4
    const float4 v = ((const float4*)x)[gl];
    float m = fmaxf(fmaxf(fabsf(v.x), fabsf(v.y)), fmaxf(fabsf(v.z), fabsf(v.w)));
    m = fmaxf(m, __shfl_xor(m, 1));
    m = fmaxf(m, __shfl_xor(m, 2));
    m = fmaxf(m, __shfl_xor(m, 4));                         // 8-lane group = 1 MX block
    const unsigned ef = __float_as_uint(m) >> 23;
    const unsigned code = (ef < 3u) ? 1u : (ef - 2u);       // FLOOR scale, clamped
    const float inv = __uint_as_float((254u - code) << 23); // exact 2^(127-code)
    const uint32_t p = enc1(v.x, inv)        | (enc1(v.y, inv) << 4)
                     | (enc1(v.z, inv) << 8) | (enc1(v.w, inv) << 12);
    ((uint16_t*)xq)[gl] = (uint16_t)p;                      // coalesced 2 B/lane
    if ((gl & 7) == 0) {
        const int blk = gl >> 3;                            // m*128 + kb
        const int mm = blk >> 7, kb = blk & 127;
        xsi[(size_t)(kb >> 3) * ((size_t)M * 8) + (size_t)mm * 8
            + ((kb & 1) << 2) + ((kb & 7) >> 1)] = (uint8_t)code;
    }
}

// ---------------------------------------------------------------------------
// Kernel 2 (merged): blocks [0,nwb): densify weight nibbles. Remaining 128
// blocks: transpose wsc int32 [n][kb] -> packed-interleaved ws_i[chunk][n][h][j]
// (byte h*4+j = scale of kb = 8*chunk + 2*j + h). Coalesced both sides.
// ---------------------------------------------------------------------------
__global__ __launch_bounds__(256) void repack_kernel(const int* __restrict__ wp,
                                                     uint32_t* __restrict__ wrep,
                                                     int nwb,
                                                     const int* __restrict__ wsc,
                                                     uint8_t* __restrict__ ws_i,
                                                     int R, int Ck) {
    const int bid = blockIdx.x;
    const int t = threadIdx.x;
    if (bid < nwb) {                              // ---- wrep densify ----
        const int i = bid * 256 + t;
        const int4 p = ((const int4*)wp)[i];
        wrep[i] = (uint32_t)(p.x & 0xFF) | ((uint32_t)(p.y & 0xFF) << 8)
                | ((uint32_t)(p.z & 0xFF) << 16) | ((uint32_t)(p.w & 0xFF) << 24);
        return;
    }
    // ---- W-scale transpose/interleave: tile 128 rows x 32 kb ----
    __shared__ uint8_t raw[128 * 32];
    const int tidx = bid - nwb;                   // 0..127
    const int n0 = (tidx & 31) * 128;             // row base (R/128 = 32)
    const int c0 = (tidx >> 5) * 32;              // kb base  (Ck/32 = 4)
    {
        const int r = t >> 1, hf = t & 1;
        const size_t base = (size_t)(n0 + r) * Ck + c0 + hf * 16;
        uint32_t b[4];
#pragma unroll
        for (int j = 0; j < 4; ++j) {
            const int4 p = *(const int4*)(wsc + base + 4 * j);
            b[j] = (uint32_t)(p.x & 0xFF) | ((uint32_t)(p.y & 0xFF) << 8)
                 | ((uint32_t)(p.z & 0xFF) << 16) | ((uint32_t)(p.w & 0xFF) << 24);
        }
        *(uint4*)(raw + r * 32 + hf * 16) = make_uint4(b[0], b[1], b[2], b[3]);
    }
    __syncthreads();
    const int ml = t & 127;
#pragma unroll
    for (int pp = 0; pp < 2; ++pp) {
        const int ckl = (t >> 7) + 2 * pp;        // local chunk 0..3
        const int base = ml * 32 + ckl * 8;
        const uint32_t lo = (uint32_t)raw[base + 0] | ((uint32_t)raw[base + 2] << 8)
                          | ((uint32_t)raw[base + 4] << 16) | ((uint32_t)raw[base + 6] << 24);
        const uint32_t hi = (uint32_t)raw[base + 1] | ((uint32_t)raw[base + 3] << 8)
                          | ((uint32_t)raw[base + 5] << 16) | ((uint32_t)raw[base + 7] << 24);
        *(uint2*)(ws_i + (size_t)(c0 / 8 + ckl) * ((size_t)R * 8)
                       + (size_t)(n0 + ml) * 8) = make_uint2(lo, hi);
    }
}

// ---------------------------------------------------------------------------
// Kernel 3: MXFP4 GEMM, 128x128 tile, BK=256, 4 waves x (2x2)
// v_mfma_scale_f32_32x32x64_f8f6f4 (fmt 4 = fp4 e2m1).  R6 structure (best,
// 55.7 us): single buffer, 2x __syncthreads, 4 blocks/CU, p=w^(r&7) swizzle.
//
// Round-10 change: scales OUT of LDS. Per chunk each lane loads ONE b32 per
// operand row from the packed-interleaved global arrays (wave pattern = 256
// contiguous bytes -> fully coalesced, L1/L2-hot), issued alongside the
// GLL16s so the barrier's vmcnt(0) drain covers both. Per-s-slice byte
// extracted by VALU shift (safe; VALU only 12% busy). Removes 2 GLL4s +
// 16 LDS byte-reads per wave per chunk and the sS buffer — the serial
// stage section shrinks and the LDS pipe (critical, ~83% busy) sheds
// ~1.5K cy/chunk/CU.
// ---------------------------------------------------------------------------
__global__ __launch_bounds__(256) void gemm_mx_kernel(const uint8_t* __restrict__ Apk,
                                                      const uint8_t* __restrict__ Bpk,
                                                      const uint8_t* __restrict__ Asi,
                                                      const uint8_t* __restrict__ Bsi,
                                                      float* __restrict__ C,
                                                      int M, int N, int K) {
    __shared__ __align__(16) uint8_t sA[16384];   // 128 rows x 128 B
    __shared__ __align__(16) uint8_t sB[16384];

    const int tid = threadIdx.x;
    const int bm0 = blockIdx.y << 7;
    const int bn0 = blockIdx.x << 7;
    const int wave = tid >> 6;
    const int lane = tid & 63;
    const int wm = (wave >> 1) << 6;
    const int wn = (wave & 1) << 6;
    const int row = lane & 31;
    const int h = lane >> 5;
    const int Kb = K >> 1;                        // packed bytes per row (2048)

    // data staging: 1024 slots/tile (128 rows x 8 pieces), 4 slots/thread.
    // slot s: row r = s>>3, within-row slot w = s&7, piece p = w ^ (r&7)
    const uint8_t* Ag[4];
    const uint8_t* Bg[4];
#pragma unroll
    for (int i = 0; i < 4; ++i) {
        const int s = tid + 256 * i;
        const int r = s >> 3;
        const int p = (s & 7) ^ (r & 7);
        Ag[i] = Apk + (size_t)(bm0 + r) * Kb + p * 16;
        Bg[i] = Bpk + (size_t)(bn0 + r) * Kb + p * 16;
    }

    const int ar0 = wm + row, ar1 = wm + 32 + row;
    const int br0 = wn + row, br1 = wn + 32 + row;

    // packed-scale bases: lane reads b32 at [chunk][row][h] (coalesced)
    const uint8_t* SgA0 = Asi + (size_t)(bm0 + ar0) * 8 + h * 4;
    const uint8_t* SgA1 = Asi + (size_t)(bm0 + ar1) * 8 + h * 4;
    const uint8_t* SgB0 = Bsi + (size_t)(bn0 + br0) * 8 + h * 4;
    const uint8_t* SgB1 = Bsi + (size_t)(bn0 + br1) * 8 + h * 4;
    const size_t sStepA = (size_t)M * 8;
    const size_t sStepB = (size_t)N * 8;

    floatx16 acc[2][2];
#pragma unroll
    for (int a = 0; a < 2; ++a)
#pragma unroll
        for (int b = 0; b < 2; ++b)
#pragma unroll
            for (int r = 0; r < 16; ++r) acc[a][b][r] = 0.f;

    const int nchunk = K >> 8;                    // 16

    for (int c = 0; c < nchunk; ++c) {
        __syncthreads();
        const size_t koff = (size_t)c << 7;       // 128 B per chunk
#pragma unroll
        for (int i = 0; i < 4; ++i) GLL16(Ag[i] + koff, sA + (tid + 256 * i) * 16);
#pragma unroll
        for (int i = 0; i < 4; ++i) GLL16(Bg[i] + koff, sB + (tid + 256 * i) * 16);
        // per-lane packed scales for this chunk (coalesced b32; latency
        // co-drains with the GLL16s at the barrier below)
        uint32_t sa32[2], sb32[2];
        sa32[0] = *(const uint32_t*)(SgA0 + c * sStepA);
        sa32[1] = *(const uint32_t*)(SgA1 + c * sStepA);
        sb32[0] = *(const uint32_t*)(SgB0 + c * sStepB);
        sb32[1] = *(const uint32_t*)(SgB1 + c * sStepB);
        __syncthreads();

#pragma unroll
        for (int s = 0; s < 4; ++s) {
            const int kp = 2 * s + h;             // 16B piece / MX-block index 0..7
            intx4 a4[2], b4[2];
            a4[0] = *(const intx4*)(sA + ar0 * 128 + ((kp ^ (ar0 & 7)) << 4));
            a4[1] = *(const intx4*)(sA + ar1 * 128 + ((kp ^ (ar1 & 7)) << 4));
            b4[0] = *(const intx4*)(sB + br0 * 128 + ((kp ^ (br0 & 7)) << 4));
            b4[1] = *(const intx4*)(sB + br1 * 128 + ((kp ^ (br1 & 7)) << 4));
            const int sa[2] = { (int)((sa32[0] >> (8 * s)) & 0xFF),
                                (int)((sa32[1] >> (8 * s)) & 0xFF) };
            const int sb[2] = { (int)((sb32[0] >> (8 * s)) & 0xFF),
                                (int)((sb32[1] >> (8 * s)) & 0xFF) };
#pragma unroll
            for (int mt = 0; mt < 2; ++mt)
#pragma unroll
                for (int nt = 0; nt < 2; ++nt) {
                    intx8 a8 = {a4[mt][0], a4[mt][1], a4[mt][2], a4[mt][3], 0, 0, 0, 0};
                    intx8 b8 = {b4[nt][0], b4[nt][1], b4[nt][2], b4[nt][3], 0, 0, 0, 0};
                    acc[mt][nt] = __builtin_amdgcn_mfma_scale_f32_32x32x64_f8f6f4(
                        a8, b8, acc[mt][nt], 4, 4, 0, sa[mt], 0, sb[nt]);
                }
        }
    }

    // C/D layout (32x32): col = lane&31, row = (reg&3) + 8*(reg>>2) + 4*(lane>>5)
#pragma unroll
    for (int mt = 0; mt < 2; ++mt)
#pragma unroll
        for (int nt = 0; nt < 2; ++nt) {
            const int col = bn0 + wn + nt * 32 + row;
#pragma unroll
            for (int g = 0; g < 4; ++g) {
                const int rw = bm0 + wm + mt * 32 + 8 * g + 4 * h;
#pragma unroll
                for (int q = 0; q < 4; ++q)
                    C[(size_t)(rw + q) * N + col] = acc[mt][nt][4 * g + q];
            }
        }
}

// ---------------------------------------------------------------------------
extern "C" void kernel_launch(void* const* d_in, const int* in_sizes, int n_in,
                              void* d_out, int out_size, void* d_ws, size_t ws_size,
                              hipStream_t stream) {
    const float* x = (const float*)d_in[0];
    const int* wp = (const int*)d_in[1];
    const int* wsc = (const int*)d_in[2];
    float* out = (float*)d_out;

    const int K = 4096;
    const int M = in_sizes[0] / K;            // 4096
    const int N = (in_sizes[1] * 2) / K;      // 4096
    const int kbpr = K / 32;                  // 128
    const int npack = N * K / 2;              // weight packed bytes

    uint32_t* xq   = (uint32_t*)d_ws;                                  // 8 MiB
    uint8_t*  xs_i = (uint8_t*)d_ws + (size_t)M * K / 2;               // 512 KiB packed-interleaved
    uint32_t* wrep = (uint32_t*)(xs_i + (size_t)M * kbpr);             // 8 MiB
    uint8_t*  ws_i = (uint8_t*)(wrep + (size_t)npack / 4);             // 512 KiB packed-interleaved

    const int nwb = npack / 4 / 256;          // wrep blocks (8192)
    const int ntb = (N / 128) * (kbpr / 32);  // W-scale transpose tiles (128)

    quant_x_kernel<<<(M * K / 4) / 256, 256, 0, stream>>>(x, xq, xs_i, M);
    repack_kernel<<<nwb + ntb, 256, 0, stream>>>(wp, wrep, nwb, wsc, ws_i, N, kbpr);

    dim3 grid(N / 128, M / 128);
    gemm_mx_kernel<<<grid, 256, 0, stream>>>((const uint8_t*)xq, (const uint8_t*)wrep,
                                             xs_i, ws_i, out, M, N, K);
}

// Round 11
// 182.950 us; speedup vs baseline: 1.1923x; 1.0463x over previous
//
#include <hip/hip_runtime.h>
#include <stdint.h>

typedef __attribute__((ext_vector_type(4)))  int   intx4;
typedef __attribute__((ext_vector_type(8)))  int   intx8;
typedef __attribute__((ext_vector_type(16))) float floatx16;

#define GLL16(gp, lp)                                                               \
    __builtin_amdgcn_global_load_lds((const __attribute__((address_space(1))) unsigned int*)(gp), \
                                     (__attribute__((address_space(3))) unsigned int*)(lp), 16, 0, 0)
#define GLL4(gp, lp)                                                                \
    __builtin_amdgcn_global_load_lds((const __attribute__((address_space(1))) unsigned int*)(gp), \
                                     (__attribute__((address_space(3))) unsigned int*)(lp), 4, 0, 0)

// ---------------------------------------------------------------------------
// RTE onto the e2m1 grid {0,.5,1,1.5,2,3,4,6} -> code 0..7 (ties-to-even,
// matches ref searchsorted+tie-fix). Sign -> bit 3. (proven)
// ---------------------------------------------------------------------------
__device__ __forceinline__ uint32_t enc1(float xv, float inv) {
    float a = fminf(fabsf(xv) * inv, 6.0f);
    int e;
    if (a < 2.0f)      e = (int)rintf(a + a);          // 0,.5,1,1.5,2 -> 0..4
    else if (a < 4.0f) e = (int)rintf(a) + 2;          // 2,3,4        -> 4..6
    else               e = (int)rintf(a * 0.5f) + 4;   // 4,6          -> 6,7
    return (uint32_t)e | ((__float_as_uint(xv) >> 28) & 8u);
}

// ---------------------------------------------------------------------------
// Kernel 1 (merged prep, single launch):
//   blocks [0, nq)            : quantize x -> xq + xs_t[kb][m] (direct
//                               scattered byte store — R10 proved cheap,
//                               L2 coalesces the stride-M bytes)
//   blocks [nq, nq+nwb)       : densify weight nibbles -> wrep
//   blocks [nq+nwb, +ntb)     : transpose wsc int32 [n][kb] -> ws_t[kb][n]
// All parts independent (read only original inputs / write disjoint arrays).
// ---------------------------------------------------------------------------
__global__ __launch_bounds__(256) void prep_kernel(const float* __restrict__ x,
                                                   uint32_t* __restrict__ xq,
                                                   uint8_t* __restrict__ xs_t,
                                                   int nq, int M,
                                                   const int* __restrict__ wp,
                                                   uint32_t* __restrict__ wrep,
                                                   int nwb,
                                                   const int* __restrict__ wsc,
                                                   uint8_t* __restrict__ ws_t,
                                                   int N, int Ck) {
    const int bid = blockIdx.x;
    const int t = threadIdx.x;
    if (bid < nq) {                               // ---- quantize x ----
        const int gl = bid * 256 + t;             // lane over M*K/4
        const float4 v = ((const float4*)x)[gl];
        float m = fmaxf(fmaxf(fabsf(v.x), fabsf(v.y)), fmaxf(fabsf(v.z), fabsf(v.w)));
        m = fmaxf(m, __shfl_xor(m, 1));
        m = fmaxf(m, __shfl_xor(m, 2));
        m = fmaxf(m, __shfl_xor(m, 4));           // 8-lane group = 1 MX block
        const unsigned ef = __float_as_uint(m) >> 23;
        const unsigned code = (ef < 3u) ? 1u : (ef - 2u);       // FLOOR scale
        const float inv = __uint_as_float((254u - code) << 23); // 2^(127-code)
        const uint32_t p = enc1(v.x, inv)        | (enc1(v.y, inv) << 4)
                         | (enc1(v.z, inv) << 8) | (enc1(v.w, inv) << 12);
        ((uint16_t*)xq)[gl] = (uint16_t)p;        // coalesced 2 B/lane
        if ((gl & 7) == 0) {                      // one scale byte / MX block
            const int blk = gl >> 3;              // m*128 + kb
            xs_t[(size_t)(blk & 127) * M + (blk >> 7)] = (uint8_t)code;
        }
        return;
    }
    if (bid < nq + nwb) {                         // ---- wrep densify ----
        const int i = (bid - nq) * 256 + t;
        const int4 p = ((const int4*)wp)[i];
        wrep[i] = (uint32_t)(p.x & 0xFF) | ((uint32_t)(p.y & 0xFF) << 8)
                | ((uint32_t)(p.z & 0xFF) << 16) | ((uint32_t)(p.w & 0xFF) << 24);
        return;
    }
    // ---- W-scale transpose: tile 128 rows x 32 kb ----
    __shared__ uint8_t raw[128 * 32];
    const int tidx = bid - nq - nwb;              // 0..127
    const int n0 = (tidx & 31) * 128;             // row base (N/128 = 32)
    const int c0 = (tidx >> 5) * 32;              // kb base  (Ck/32 = 4)
    {
        const int r = t >> 1, hf = t & 1;
        const size_t base = (size_t)(n0 + r) * Ck + c0 + hf * 16;
        uint32_t b[4];
#pragma unroll
        for (int j = 0; j < 4; ++j) {
            const int4 p = *(const int4*)(wsc + base + 4 * j);
            b[j] = (uint32_t)(p.x & 0xFF) | ((uint32_t)(p.y & 0xFF) << 8)
                 | ((uint32_t)(p.z & 0xFF) << 16) | ((uint32_t)(p.w & 0xFF) << 24);
        }
        *(uint4*)(raw + r * 32 + hf * 16) = make_uint4(b[0], b[1], b[2], b[3]);
    }
    __syncthreads();
    const int c = t >> 3, q = t & 7;
    uint32_t d[4];
#pragma unroll
    for (int j = 0; j < 4; ++j) {
        const int mb = q * 16 + j * 4;
        d[j] = (uint32_t)raw[(mb + 0) * 32 + c]
             | ((uint32_t)raw[(mb + 1) * 32 + c] << 8)
             | ((uint32_t)raw[(mb + 2) * 32 + c] << 16)
             | ((uint32_t)raw[(mb + 3) * 32 + c] << 24);
    }
    *(uint4*)(ws_t + (size_t)(c0 + c) * N + n0 + q * 16) = make_uint4(d[0], d[1], d[2], d[3]);
}

// ---------------------------------------------------------------------------
// Kernel 2: MXFP4 GEMM — BIT-IDENTICAL revert to round 6 (best: 55.7 us).
// 128x128 tile, BK=256, 4 waves x (2x2), single buffer, 2x __syncthreads,
// 4 blocks/CU, piece swizzle p = w ^ (r&7) (conflicts 12.58M -> 4.19M),
// coalesced transposed-scale GLL4 staging into sS ([kb-slice][row], byte
// reads broadcast-free). Five structural variants (dbuf/P2, B-to-reg,
// scales-to-reg, XCD remap, 128x256) all measured worse — this is the
// structure's local optimum.
// ---------------------------------------------------------------------------
__global__ __launch_bounds__(256) void gemm_mx_kernel(const uint8_t* __restrict__ Apk,
                                                      const uint8_t* __restrict__ Bpk,
                                                      const uint8_t* __restrict__ AsT,
                                                      const uint8_t* __restrict__ BsT,
                                                      float* __restrict__ C,
                                                      int M, int N, int K) {
    __shared__ __align__(16) uint8_t sA[16384];   // 128 rows x 128 B
    __shared__ __align__(16) uint8_t sB[16384];
    __shared__ __align__(16) uint8_t sS[2048];    // [A kb0..7][row] | [B kb0..7][row]

    const int tid = threadIdx.x;
    const int bm0 = blockIdx.y << 7;
    const int bn0 = blockIdx.x << 7;
    const int wave = tid >> 6;
    const int lane = tid & 63;
    const int wm = (wave >> 1) << 6;
    const int wn = (wave & 1) << 6;
    const int row = lane & 31;
    const int h = lane >> 5;
    const int Kb = K >> 1;                        // packed bytes per row (2048)

    // data staging: 1024 slots/tile (128 rows x 8 pieces), 4 slots/thread.
    // slot s: row r = s>>3, within-row slot w = s&7, piece p = w ^ (r&7)
    const uint8_t* Ag[4];
    const uint8_t* Bg[4];
#pragma unroll
    for (int i = 0; i < 4; ++i) {
        const int s = tid + 256 * i;
        const int r = s >> 3;
        const int p = (s & 7) ^ (r & 7);
        Ag[i] = Apk + (size_t)(bm0 + r) * Kb + p * 16;
        Bg[i] = Bpk + (size_t)(bn0 + r) * Kb + p * 16;
    }

    // scale staging (coalesced, transposed arrays): waves 0-1 -> A, 2-3 -> B.
    // Chunk c covers kb slices 8c..8c+7; GLL4 #1 stages slices 0-3, #2 4-7.
    const int st = tid & 127;
    const int sj = st >> 5, si = st & 31;
    const size_t sR = (size_t)((tid < 128) ? M : N);
    const uint8_t* Sg1 = ((tid < 128) ? (AsT + (size_t)sj * M + bm0)
                                      : (BsT + (size_t)sj * N + bn0)) + si * 4;
    const uint8_t* Sg2 = Sg1 + 4 * sR;
    const size_t sAdv = 8 * sR;
    const int soff = ((tid < 128) ? 0 : 1024) + st * 4;

    floatx16 acc[2][2];
#pragma unroll
    for (int a = 0; a < 2; ++a)
#pragma unroll
        for (int b = 0; b < 2; ++b)
#pragma unroll
            for (int r = 0; r < 16; ++r) acc[a][b][r] = 0.f;

    const int nchunk = K >> 8;                    // 16
    const int ar0 = wm + row, ar1 = wm + 32 + row;
    const int br0 = wn + row, br1 = wn + 32 + row;

    for (int c = 0; c < nchunk; ++c) {
        __syncthreads();
        const size_t koff = (size_t)c << 7;       // 128 B per chunk
#pragma unroll
        for (int i = 0; i < 4; ++i) GLL16(Ag[i] + koff, sA + (tid + 256 * i) * 16);
#pragma unroll
        for (int i = 0; i < 4; ++i) GLL16(Bg[i] + koff, sB + (tid + 256 * i) * 16);
        GLL4(Sg1 + (size_t)c * sAdv, sS + soff);
        GLL4(Sg2 + (size_t)c * sAdv, sS + soff + 512);
        __syncthreads();

#pragma unroll
        for (int s = 0; s < 4; ++s) {
            const int kp = 2 * s + h;             // 16B piece / MX-block index 0..7
            intx4 a4[2], b4[2];
            int sa[2], sb[2];
            a4[0] = *(const intx4*)(sA + ar0 * 128 + ((kp ^ (ar0 & 7)) << 4));
            a4[1] = *(const intx4*)(sA + ar1 * 128 + ((kp ^ (ar1 & 7)) << 4));
            b4[0] = *(const intx4*)(sB + br0 * 128 + ((kp ^ (br0 & 7)) << 4));
            b4[1] = *(const intx4*)(sB + br1 * 128 + ((kp ^ (br1 & 7)) << 4));
            sa[0] = sS[kp * 128 + ar0];
            sa[1] = sS[kp * 128 + ar1];
            sb[0] = sS[1024 + kp * 128 + br0];
            sb[1] = sS[1024 + kp * 128 + br1];
#pragma unroll
            for (int mt = 0; mt < 2; ++mt)
#pragma unroll
                for (int nt = 0; nt < 2; ++nt) {
                    intx8 a8 = {a4[mt][0], a4[mt][1], a4[mt][2], a4[mt][3], 0, 0, 0, 0};
                    intx8 b8 = {b4[nt][0], b4[nt][1], b4[nt][2], b4[nt][3], 0, 0, 0, 0};
                    acc[mt][nt] = __builtin_amdgcn_mfma_scale_f32_32x32x64_f8f6f4(
                        a8, b8, acc[mt][nt], 4, 4, 0, sa[mt], 0, sb[nt]);
                }
        }
    }

    // C/D layout (32x32): col = lane&31, row = (reg&3) + 8*(reg>>2) + 4*(lane>>5)
#pragma unroll
    for (int mt = 0; mt < 2; ++mt)
#pragma unroll
        for (int nt = 0; nt < 2; ++nt) {
            const int col = bn0 + wn + nt * 32 + row;
#pragma unroll
            for (int g = 0; g < 4; ++g) {
                const int rw = bm0 + wm + mt * 32 + 8 * g + 4 * h;
#pragma unroll
                for (int q = 0; q < 4; ++q)
                    C[(size_t)(rw + q) * N + col] = acc[mt][nt][4 * g + q];
            }
        }
}

// ---------------------------------------------------------------------------
extern "C" void kernel_launch(void* const* d_in, const int* in_sizes, int n_in,
                              void* d_out, int out_size, void* d_ws, size_t ws_size,
                              hipStream_t stream) {
    const float* x = (const float*)d_in[0];
    const int* wp = (const int*)d_in[1];
    const int* wsc = (const int*)d_in[2];
    float* out = (float*)d_out;

    const int K = 4096;
    const int M = in_sizes[0] / K;            // 4096
    const int N = (in_sizes[1] * 2) / K;      // 4096
    const int kbpr = K / 32;                  // 128
    const int npack = N * K / 2;              // weight packed bytes

    uint32_t* xq   = (uint32_t*)d_ws;                                  // 8 MiB
    uint8_t*  xs_t = (uint8_t*)d_ws + (size_t)M * K / 2;               // 512 KiB [kb][m]
    uint32_t* wrep = (uint32_t*)(xs_t + (size_t)M * kbpr);             // 8 MiB
    uint8_t*  ws_t = (uint8_t*)(wrep + (size_t)npack / 4);             // 512 KiB [kb][n]

    const int nq  = (M * K / 4) / 256;        // quant blocks (16384)
    const int nwb = npack / 4 / 256;          // wrep blocks (8192)
    const int ntb = (N / 128) * (kbpr / 32);  // W-scale transpose tiles (128)

    prep_kernel<<<nq + nwb + ntb, 256, 0, stream>>>(x, xq, xs_t, nq, M,
                                                    wp, wrep, nwb,
                                                    wsc, ws_t, N, kbpr);

    dim3 grid(N / 128, M / 128);
    gemm_mx_kernel<<<grid, 256, 0, stream>>>((const uint8_t*)xq, (const uint8_t*)wrep,
                                             xs_t, ws_t, out, M, N, K);
}